// Round 4
// baseline (3644.481 us; speedup 1.0000x reference)
//
#include <hip/hip_runtime.h>
#include <hip/hip_bf16.h>

#define IN_DIM 128
#define HID 64
#define BM 128
#define BKP 16
#define SCAN_B 1024

// ---- proj1: [xW | xWr] = x @ [Wl1 | Wr1]  (N x 128) @ (128 x 128) ---------
// BK=16, register-prefetch double-buffer, conflict-tuned LDS layouts.
__global__ __launch_bounds__(256) void proj1_kernel(
    const float* __restrict__ x, const float* __restrict__ Wl,
    const float* __restrict__ Wr, float* __restrict__ xW,
    float* __restrict__ xWr, int N) {
  __shared__ float xs[BKP][132];  // padded: stage-writes 2-way (free)
  __shared__ float ws[BKP][128];  // slot-permuted W tile
  const int tx = threadIdx.x;
  const int c = tx & 15;  // col group: logical cols c*8 .. c*8+7
  const int r = tx >> 4;  // node group: nodes r*8 .. r*8+7
  const int n0 = blockIdx.x * BM;

  // x staging map: thread stages 8 k-values of one node
  const int xn = tx >> 1;
  const int xko = (tx & 1) * 8;
  const int gnode = n0 + xn;
  // W staging map: thread stages logical cols wc*8..wc*8+7 of row wk
  const int wk = tx >> 4;
  const int wc = tx & 15;
  const int wL = wc * 8;  // 0..120, never straddles the Wl/Wr split

  float4 px0, px1, pw0, pw1;
  const float4 fz = {0.f, 0.f, 0.f, 0.f};

  auto issue = [&](int k0) {
    if (gnode < N) {
      const float* xp = &x[(size_t)gnode * IN_DIM + k0 + xko];
      px0 = *(const float4*)(xp);
      px1 = *(const float4*)(xp + 4);
    } else {
      px0 = fz;
      px1 = fz;
    }
    const float* wbase = (wL < 64)
                             ? &Wl[(size_t)(k0 + wk) * HID + wL]
                             : &Wr[(size_t)(k0 + wk) * HID + (wL - 64)];
    pw0 = *(const float4*)(wbase);
    pw1 = *(const float4*)(wbase + 4);
  };

  float acc[8][8];
#pragma unroll
  for (int i = 0; i < 8; ++i)
#pragma unroll
    for (int j = 0; j < 8; ++j) acc[i][j] = 0.f;

  issue(0);
#pragma unroll
  for (int it = 0; it < 8; ++it) {
    // stage current tile into LDS
    xs[xko + 0][xn] = px0.x;
    xs[xko + 1][xn] = px0.y;
    xs[xko + 2][xn] = px0.z;
    xs[xko + 3][xn] = px0.w;
    xs[xko + 4][xn] = px1.x;
    xs[xko + 5][xn] = px1.y;
    xs[xko + 6][xn] = px1.z;
    xs[xko + 7][xn] = px1.w;
    // phys(L) = ((L&4)<<4) + ((L>>3)<<2) + (L&3): halves land at slots wc, 16+wc
    *(float4*)&ws[wk][wc * 4] = pw0;
    *(float4*)&ws[wk][64 + wc * 4] = pw1;
    __syncthreads();
    if (it < 7) issue((it + 1) * BKP);  // prefetch overlaps compute
#pragma unroll
    for (int k = 0; k < BKP; ++k) {
      float a[8], b[8];
      *(float4*)&a[0] = *(const float4*)&xs[k][r * 8];
      *(float4*)&a[4] = *(const float4*)&xs[k][r * 8 + 4];
      *(float4*)&b[0] = *(const float4*)&ws[k][c * 4];
      *(float4*)&b[4] = *(const float4*)&ws[k][64 + c * 4];
#pragma unroll
      for (int i = 0; i < 8; ++i)
#pragma unroll
        for (int j = 0; j < 8; ++j) acc[i][j] += a[i] * b[j];
    }
    __syncthreads();
  }
#pragma unroll
  for (int i = 0; i < 8; ++i) {
    const int n = n0 + r * 8 + i;
    if (n < N) {
      float* dst = (c < 8) ? &xW[(size_t)n * HID + c * 8]
                           : &xWr[(size_t)n * HID + (c - 8) * 8];
      *(float4*)&dst[0] = *(float4*)&acc[i][0];
      *(float4*)&dst[4] = *(float4*)&acc[i][4];
    }
  }
}

// ---- CSR build ------------------------------------------------------------
__global__ __launch_bounds__(256) void count_kernel(const int* __restrict__ ei,
                                                    int* __restrict__ deg_i,
                                                    int E) {
  const int e = blockIdx.x * blockDim.x + threadIdx.x;
  if (e < E) atomicAdd(&deg_i[ei[E + e]], 1);
}

__global__ __launch_bounds__(SCAN_B) void scan1_kernel(
    const int* __restrict__ in, int* __restrict__ incl, int* __restrict__ bsum,
    int n) {
  __shared__ int s[SCAN_B];
  const int t = threadIdx.x;
  const int i = blockIdx.x * SCAN_B + t;
  int v = (i < n) ? in[i] : 0;
  s[t] = v;
  for (int off = 1; off < SCAN_B; off <<= 1) {
    __syncthreads();
    const int a = (t >= off) ? s[t - off] : 0;
    __syncthreads();
    s[t] += a;
  }
  if (i < n) incl[i] = s[t];
  if (t == SCAN_B - 1) bsum[blockIdx.x] = s[t];
}

__global__ __launch_bounds__(SCAN_B) void scan2_kernel(
    const int* __restrict__ bsum, int* __restrict__ boff, int nb) {
  __shared__ int s[SCAN_B];
  const int t = threadIdx.x;
  const int v = (t < nb) ? bsum[t] : 0;
  s[t] = v;
  for (int off = 1; off < SCAN_B; off <<= 1) {
    __syncthreads();
    const int a = (t >= off) ? s[t - off] : 0;
    __syncthreads();
    s[t] += a;
  }
  if (t < nb) boff[t] = s[t] - v;  // exclusive
}

__global__ __launch_bounds__(256) void scan3_kernel(
    const int* __restrict__ incl, const int* __restrict__ deg_i,
    const int* __restrict__ boff, int* __restrict__ row_off,
    int* __restrict__ cursor, int n) {
  const int i = blockIdx.x * blockDim.x + threadIdx.x;
  if (i < n) {
    const int st = incl[i] - deg_i[i] + boff[i >> 10];
    row_off[i] = st;
    cursor[i] = st;
  }
}

__global__ __launch_bounds__(256) void fill_kernel(const int* __restrict__ ei,
                                                   int* __restrict__ cursor,
                                                   int* __restrict__ csr_src,
                                                   int E) {
  const int e = blockIdx.x * blockDim.x + threadIdx.x;
  if (e < E) {
    const int s = ei[e];
    const int d = ei[E + e];
    const int pos = atomicAdd(&cursor[d], 1);
    csr_src[pos] = s;
  }
}

// ---- gather1: agg = sum_j xW[src]; h = relu(agg/deg + xWr + b1);
//      pl = h @ Wl2, pr = h @ Wr2  (all fused, wave per node) ---------------
__global__ __launch_bounds__(256) void gather1_kernel(
    const int* __restrict__ row_off, const int* __restrict__ deg_i,
    const int* __restrict__ csr_src, const float* __restrict__ xW,
    const float* __restrict__ xWr, const float* __restrict__ b1,
    const float* __restrict__ Wl2, const float* __restrict__ Wr2,
    float* __restrict__ pl, float* __restrict__ pr, int N) {
  const int lane = threadIdx.x & 63;
  const float wl0 = Wl2[lane * 3 + 0], wl1 = Wl2[lane * 3 + 1],
              wl2v = Wl2[lane * 3 + 2];
  const float wr0 = Wr2[lane * 3 + 0], wr1 = Wr2[lane * 3 + 1],
              wr2v = Wr2[lane * 3 + 2];
  const float bb = b1[lane];
  const int wave = (blockIdx.x * blockDim.x + threadIdx.x) >> 6;
  const int nwaves = (gridDim.x * blockDim.x) >> 6;
  for (int n = wave; n < N; n += nwaves) {
    const int start = row_off[n];
    const int dg = deg_i[n];
    float a0 = 0.f, a1 = 0.f;
    int r = 0;
    for (; r + 1 < dg; r += 2) {
      const int s0 = csr_src[start + r];
      const int s1 = csr_src[start + r + 1];
      a0 += xW[(size_t)s0 * HID + lane];
      a1 += xW[(size_t)s1 * HID + lane];
    }
    if (r < dg) a0 += xW[(size_t)csr_src[start + r] * HID + lane];
    const float dinv = 1.0f / fmaxf((float)dg, 1.0f);
    const float hv =
        fmaxf((a0 + a1) * dinv + xWr[(size_t)n * HID + lane] + bb, 0.0f);
    float v0 = hv * wl0, v1 = hv * wl1, v2 = hv * wl2v;
    float v3 = hv * wr0, v4 = hv * wr1, v5 = hv * wr2v;
#pragma unroll
    for (int off = 32; off >= 1; off >>= 1) {
      v0 += __shfl_down(v0, off);
      v1 += __shfl_down(v1, off);
      v2 += __shfl_down(v2, off);
      v3 += __shfl_down(v3, off);
      v4 += __shfl_down(v4, off);
      v5 += __shfl_down(v5, off);
    }
    if (lane == 0) {
      pl[(size_t)n * 3 + 0] = v0;
      pl[(size_t)n * 3 + 1] = v1;
      pl[(size_t)n * 3 + 2] = v2;
      pr[(size_t)n * 3 + 0] = v3;
      pr[(size_t)n * 3 + 1] = v4;
      pr[(size_t)n * 3 + 2] = v5;
    }
  }
}

// ---- final: gather pl over neighbors, log_softmax -------------------------
__global__ __launch_bounds__(256) void final_kernel(
    const int* __restrict__ row_off, const int* __restrict__ deg_i,
    const int* __restrict__ csr_src, const float* __restrict__ pl,
    const float* __restrict__ pr, const float* __restrict__ b2,
    float* __restrict__ out, int N) {
  const int stride = gridDim.x * blockDim.x;
  const float b20 = b2[0], b21 = b2[1], b22 = b2[2];
  for (int n = blockIdx.x * blockDim.x + threadIdx.x; n < N; n += stride) {
    const int start = row_off[n];
    const int dg = deg_i[n];
    float s0 = 0.f, s1 = 0.f, s2 = 0.f;
    for (int r = 0; r < dg; ++r) {
      const int s = csr_src[start + r];
      s0 += pl[(size_t)s * 3 + 0];
      s1 += pl[(size_t)s * 3 + 1];
      s2 += pl[(size_t)s * 3 + 2];
    }
    const float dinv = 1.0f / fmaxf((float)dg, 1.0f);
    const float v0 = s0 * dinv + pr[(size_t)n * 3 + 0] + b20;
    const float v1 = s1 * dinv + pr[(size_t)n * 3 + 1] + b21;
    const float v2 = s2 * dinv + pr[(size_t)n * 3 + 2] + b22;
    const float m = fmaxf(fmaxf(v0, v1), v2);
    const float e0 = __expf(v0 - m), e1 = __expf(v1 - m), e2 = __expf(v2 - m);
    const float lse = __logf(e0 + e1 + e2);
    out[(size_t)n * 3 + 0] = v0 - m - lse;
    out[(size_t)n * 3 + 1] = v1 - m - lse;
    out[(size_t)n * 3 + 2] = v2 - m - lse;
  }
}

extern "C" void kernel_launch(void* const* d_in, const int* in_sizes, int n_in,
                              void* d_out, int out_size, void* d_ws,
                              size_t ws_size, hipStream_t stream) {
  const float* x = (const float*)d_in[0];
  const int* ei = (const int*)d_in[1];  // int32 (JAX x64 disabled)
  const float* Wl1 = (const float*)d_in[2];
  const float* Wr1 = (const float*)d_in[3];
  const float* b1 = (const float*)d_in[4];
  const float* Wl2 = (const float*)d_in[5];
  const float* Wr2 = (const float*)d_in[6];
  const float* b2 = (const float*)d_in[7];
  float* out = (float*)d_out;

  const int N = in_sizes[0] / IN_DIM;
  const int E = in_sizes[1] / 2;
  const int nb1 = (N + SCAN_B - 1) / SCAN_B;

  int* wsI = (int*)d_ws;
  int* deg_i = wsI;              // [N]
  int* row_off = deg_i + N;      // [N]
  int* cursor = row_off + N;     // [N]
  int* incl = cursor + N;        // [N]
  int* bsum = incl + N;          // [SCAN_B]
  int* boff = bsum + SCAN_B;     // [SCAN_B]
  int* csr_src = boff + SCAN_B;  // [E]
  float* xW = (float*)(csr_src + E);  // [N*64]
  float* xWr = xW + (size_t)N * HID;  // [N*64]
  float* pl = xWr + (size_t)N * HID;  // [N*3]
  float* pr = pl + (size_t)N * 3;     // [N*3]

  hipMemsetAsync(deg_i, 0, (size_t)N * sizeof(int), stream);

  proj1_kernel<<<(N + BM - 1) / BM, 256, 0, stream>>>(x, Wl1, Wr1, xW, xWr, N);
  count_kernel<<<(E + 255) / 256, 256, 0, stream>>>(ei, deg_i, E);
  scan1_kernel<<<nb1, SCAN_B, 0, stream>>>(deg_i, incl, bsum, N);
  scan2_kernel<<<1, SCAN_B, 0, stream>>>(bsum, boff, nb1);
  scan3_kernel<<<(N + 255) / 256, 256, 0, stream>>>(incl, deg_i, boff, row_off,
                                                    cursor, N);
  fill_kernel<<<(E + 255) / 256, 256, 0, stream>>>(ei, cursor, csr_src, E);
  gather1_kernel<<<2048, 256, 0, stream>>>(row_off, deg_i, csr_src, xW, xWr,
                                           b1, Wl2, Wr2, pl, pr, N);
  final_kernel<<<(N + 255) / 256, 256, 0, stream>>>(row_off, deg_i, csr_src,
                                                    pl, pr, b2, out, N);
}

// Round 5
// 187.176 us; speedup vs baseline: 19.4708x; 19.4708x over previous
//
#include <hip/hip_runtime.h>
#include <hip/hip_bf16.h>

#define IN_DIM 128
#define HID 64
#define BM 64
#define BK 32
#define SCAN_B 1024

// ---- proj1: [xW | xWr] = x @ [Wl1 | Wr1]  (N x 128) @ (128 x 128) ---------
// BM=64 tile, 256 thr, each thread 4 nodes x 8 cols. Plain 2-barrier loop,
// unroll 1 to prevent cross-barrier load hoisting (R4 spill lesson).
__global__ __launch_bounds__(256) void proj1_kernel(
    const float* __restrict__ x, const float* __restrict__ Wl,
    const float* __restrict__ Wr, float* __restrict__ xW,
    float* __restrict__ xWr, int N) {
  __shared__ float xs[BK][BM + 1];  // [k][node], stride 65
  __shared__ float ws[BK][132];     // [k][col],  stride 132
  const int tx = threadIdx.x;
  const int c = tx & 15;  // col group: cols c*8 .. c*8+7
  const int r = tx >> 4;  // node group: nodes r*4 .. r*4+3
  const int n0 = blockIdx.x * BM;

  // x staging: node xn = tx>>2 (0..63), k-offset xko = (tx&3)*8
  const int xn = tx >> 2;
  const int xko = (tx & 3) * 8;
  const int gnode = n0 + xn;
  // W staging: row wk = tx>>3 (0..31), cols wc = (tx&7)*16 .. +15
  const int wk = tx >> 3;
  const int wc = (tx & 7) * 16;

  float acc[4][8];
#pragma unroll
  for (int i = 0; i < 4; ++i)
#pragma unroll
    for (int j = 0; j < 8; ++j) acc[i][j] = 0.f;

#pragma unroll 1
  for (int k0 = 0; k0 < IN_DIM; k0 += BK) {
    float4 xa0, xa1;
    if (gnode < N) {
      const float* xp = &x[(size_t)gnode * IN_DIM + k0 + xko];
      xa0 = *(const float4*)(xp);
      xa1 = *(const float4*)(xp + 4);
    } else {
      xa0 = make_float4(0.f, 0.f, 0.f, 0.f);
      xa1 = make_float4(0.f, 0.f, 0.f, 0.f);
    }
    float4 wv0, wv1, wv2, wv3;
    {
      const int col = wc;  // wc is a multiple of 16; never straddles 64
      const float* wbase = (col < 64)
                               ? &Wl[(size_t)(k0 + wk) * HID + col]
                               : &Wr[(size_t)(k0 + wk) * HID + (col - 64)];
      wv0 = *(const float4*)(wbase);
      wv1 = *(const float4*)(wbase + 4);
      wv2 = *(const float4*)(wbase + 8);
      wv3 = *(const float4*)(wbase + 12);
    }
    xs[xko + 0][xn] = xa0.x;
    xs[xko + 1][xn] = xa0.y;
    xs[xko + 2][xn] = xa0.z;
    xs[xko + 3][xn] = xa0.w;
    xs[xko + 4][xn] = xa1.x;
    xs[xko + 5][xn] = xa1.y;
    xs[xko + 6][xn] = xa1.z;
    xs[xko + 7][xn] = xa1.w;
    *(float4*)&ws[wk][wc + 0] = wv0;
    *(float4*)&ws[wk][wc + 4] = wv1;
    *(float4*)&ws[wk][wc + 8] = wv2;
    *(float4*)&ws[wk][wc + 12] = wv3;
    __syncthreads();
#pragma unroll
    for (int k = 0; k < BK; ++k) {
      float a[4], b[8];
      *(float4*)&a[0] = *(const float4*)&xs[k][r * 4];
      *(float4*)&b[0] = *(const float4*)&ws[k][c * 8];
      *(float4*)&b[4] = *(const float4*)&ws[k][c * 8 + 4];
#pragma unroll
      for (int i = 0; i < 4; ++i)
#pragma unroll
        for (int j = 0; j < 8; ++j) acc[i][j] += a[i] * b[j];
    }
    __syncthreads();
  }
#pragma unroll
  for (int i = 0; i < 4; ++i) {
    const int n = n0 + r * 4 + i;
    if (n < N) {
      float* dst = (c < 8) ? &xW[(size_t)n * HID + c * 8]
                           : &xWr[(size_t)n * HID + (c - 8) * 8];
      *(float4*)&dst[0] = *(float4*)&acc[i][0];
      *(float4*)&dst[4] = *(float4*)&acc[i][4];
    }
  }
}

// ---- CSR build ------------------------------------------------------------
__global__ __launch_bounds__(256) void count_kernel(const int* __restrict__ ei,
                                                    int* __restrict__ deg_i,
                                                    int E) {
  const int e = blockIdx.x * blockDim.x + threadIdx.x;
  if (e < E) atomicAdd(&deg_i[ei[E + e]], 1);
}

__global__ __launch_bounds__(SCAN_B) void scan1_kernel(
    const int* __restrict__ in, int* __restrict__ incl, int* __restrict__ bsum,
    int n) {
  __shared__ int s[SCAN_B];
  const int t = threadIdx.x;
  const int i = blockIdx.x * SCAN_B + t;
  int v = (i < n) ? in[i] : 0;
  s[t] = v;
  for (int off = 1; off < SCAN_B; off <<= 1) {
    __syncthreads();
    const int a = (t >= off) ? s[t - off] : 0;
    __syncthreads();
    s[t] += a;
  }
  if (i < n) incl[i] = s[t];
  if (t == SCAN_B - 1) bsum[blockIdx.x] = s[t];
}

__global__ __launch_bounds__(SCAN_B) void scan2_kernel(
    const int* __restrict__ bsum, int* __restrict__ boff, int nb) {
  __shared__ int s[SCAN_B];
  const int t = threadIdx.x;
  const int v = (t < nb) ? bsum[t] : 0;
  s[t] = v;
  for (int off = 1; off < SCAN_B; off <<= 1) {
    __syncthreads();
    const int a = (t >= off) ? s[t - off] : 0;
    __syncthreads();
    s[t] += a;
  }
  if (t < nb) boff[t] = s[t] - v;  // exclusive
}

__global__ __launch_bounds__(256) void scan3_kernel(
    const int* __restrict__ incl, const int* __restrict__ deg_i,
    const int* __restrict__ boff, int* __restrict__ row_off,
    int* __restrict__ cursor, int n) {
  const int i = blockIdx.x * blockDim.x + threadIdx.x;
  if (i < n) {
    const int st = incl[i] - deg_i[i] + boff[i >> 10];
    row_off[i] = st;
    cursor[i] = st;
  }
}

__global__ __launch_bounds__(256) void fill_kernel(const int* __restrict__ ei,
                                                   int* __restrict__ cursor,
                                                   int* __restrict__ csr_src,
                                                   int E) {
  const int e = blockIdx.x * blockDim.x + threadIdx.x;
  if (e < E) {
    const int s = ei[e];
    const int d = ei[E + e];
    const int pos = atomicAdd(&cursor[d], 1);
    csr_src[pos] = s;
  }
}

// ---- gather1: agg = sum_j xW[src]; h = relu(agg/deg + xWr + b1);
//      pl = h @ Wl2, pr = h @ Wr2  (all fused, wave per node) ---------------
__global__ __launch_bounds__(256) void gather1_kernel(
    const int* __restrict__ row_off, const int* __restrict__ deg_i,
    const int* __restrict__ csr_src, const float* __restrict__ xW,
    const float* __restrict__ xWr, const float* __restrict__ b1,
    const float* __restrict__ Wl2, const float* __restrict__ Wr2,
    float* __restrict__ pl, float* __restrict__ pr, int N) {
  const int lane = threadIdx.x & 63;
  const float wl0 = Wl2[lane * 3 + 0], wl1 = Wl2[lane * 3 + 1],
              wl2v = Wl2[lane * 3 + 2];
  const float wr0 = Wr2[lane * 3 + 0], wr1 = Wr2[lane * 3 + 1],
              wr2v = Wr2[lane * 3 + 2];
  const float bb = b1[lane];
  const int wave = (blockIdx.x * blockDim.x + threadIdx.x) >> 6;
  const int nwaves = (gridDim.x * blockDim.x) >> 6;
  for (int n = wave; n < N; n += nwaves) {
    const int start = row_off[n];
    const int dg = deg_i[n];
    float a0 = 0.f, a1 = 0.f, a2 = 0.f, a3 = 0.f;
    int r = 0;
    for (; r + 3 < dg; r += 4) {
      const int s0 = csr_src[start + r];
      const int s1 = csr_src[start + r + 1];
      const int s2 = csr_src[start + r + 2];
      const int s3 = csr_src[start + r + 3];
      a0 += xW[(size_t)s0 * HID + lane];
      a1 += xW[(size_t)s1 * HID + lane];
      a2 += xW[(size_t)s2 * HID + lane];
      a3 += xW[(size_t)s3 * HID + lane];
    }
    for (; r < dg; ++r) a0 += xW[(size_t)csr_src[start + r] * HID + lane];
    const float dinv = 1.0f / fmaxf((float)dg, 1.0f);
    const float hv = fmaxf(
        ((a0 + a1) + (a2 + a3)) * dinv + xWr[(size_t)n * HID + lane] + bb,
        0.0f);
    float v0 = hv * wl0, v1 = hv * wl1, v2 = hv * wl2v;
    float v3 = hv * wr0, v4 = hv * wr1, v5 = hv * wr2v;
#pragma unroll
    for (int off = 32; off >= 1; off >>= 1) {
      v0 += __shfl_down(v0, off);
      v1 += __shfl_down(v1, off);
      v2 += __shfl_down(v2, off);
      v3 += __shfl_down(v3, off);
      v4 += __shfl_down(v4, off);
      v5 += __shfl_down(v5, off);
    }
    if (lane == 0) {
      pl[(size_t)n * 3 + 0] = v0;
      pl[(size_t)n * 3 + 1] = v1;
      pl[(size_t)n * 3 + 2] = v2;
      pr[(size_t)n * 3 + 0] = v3;
      pr[(size_t)n * 3 + 1] = v4;
      pr[(size_t)n * 3 + 2] = v5;
    }
  }
}

// ---- final: gather pl over neighbors, log_softmax -------------------------
__global__ __launch_bounds__(256) void final_kernel(
    const int* __restrict__ row_off, const int* __restrict__ deg_i,
    const int* __restrict__ csr_src, const float* __restrict__ pl,
    const float* __restrict__ pr, const float* __restrict__ b2,
    float* __restrict__ out, int N) {
  const int stride = gridDim.x * blockDim.x;
  const float b20 = b2[0], b21 = b2[1], b22 = b2[2];
  for (int n = blockIdx.x * blockDim.x + threadIdx.x; n < N; n += stride) {
    const int start = row_off[n];
    const int dg = deg_i[n];
    float s0 = 0.f, s1 = 0.f, s2 = 0.f;
    for (int r = 0; r < dg; ++r) {
      const int s = csr_src[start + r];
      s0 += pl[(size_t)s * 3 + 0];
      s1 += pl[(size_t)s * 3 + 1];
      s2 += pl[(size_t)s * 3 + 2];
    }
    const float dinv = 1.0f / fmaxf((float)dg, 1.0f);
    const float v0 = s0 * dinv + pr[(size_t)n * 3 + 0] + b20;
    const float v1 = s1 * dinv + pr[(size_t)n * 3 + 1] + b21;
    const float v2 = s2 * dinv + pr[(size_t)n * 3 + 2] + b22;
    const float m = fmaxf(fmaxf(v0, v1), v2);
    const float e0 = __expf(v0 - m), e1 = __expf(v1 - m), e2 = __expf(v2 - m);
    const float lse = __logf(e0 + e1 + e2);
    out[(size_t)n * 3 + 0] = v0 - m - lse;
    out[(size_t)n * 3 + 1] = v1 - m - lse;
    out[(size_t)n * 3 + 2] = v2 - m - lse;
  }
}

extern "C" void kernel_launch(void* const* d_in, const int* in_sizes, int n_in,
                              void* d_out, int out_size, void* d_ws,
                              size_t ws_size, hipStream_t stream) {
  const float* x = (const float*)d_in[0];
  const int* ei = (const int*)d_in[1];  // int32 (JAX x64 disabled)
  const float* Wl1 = (const float*)d_in[2];
  const float* Wr1 = (const float*)d_in[3];
  const float* b1 = (const float*)d_in[4];
  const float* Wl2 = (const float*)d_in[5];
  const float* Wr2 = (const float*)d_in[6];
  const float* b2 = (const float*)d_in[7];
  float* out = (float*)d_out;

  const int N = in_sizes[0] / IN_DIM;
  const int E = in_sizes[1] / 2;
  const int nb1 = (N + SCAN_B - 1) / SCAN_B;

  int* wsI = (int*)d_ws;
  int* deg_i = wsI;              // [N]
  int* row_off = deg_i + N;      // [N]
  int* cursor = row_off + N;     // [N]
  int* incl = cursor + N;        // [N]
  int* bsum = incl + N;          // [SCAN_B]
  int* boff = bsum + SCAN_B;     // [SCAN_B]
  int* csr_src = boff + SCAN_B;  // [E]
  float* xW = (float*)(csr_src + E);  // [N*64]
  float* xWr = xW + (size_t)N * HID;  // [N*64]
  float* pl = xWr + (size_t)N * HID;  // [N*3]
  float* pr = pl + (size_t)N * 3;     // [N*3]

  hipMemsetAsync(deg_i, 0, (size_t)N * sizeof(int), stream);

  proj1_kernel<<<(N + BM - 1) / BM, 256, 0, stream>>>(x, Wl1, Wr1, xW, xWr, N);
  count_kernel<<<(E + 255) / 256, 256, 0, stream>>>(ei, deg_i, E);
  scan1_kernel<<<nb1, SCAN_B, 0, stream>>>(deg_i, incl, bsum, N);
  scan2_kernel<<<1, SCAN_B, 0, stream>>>(bsum, boff, nb1);
  scan3_kernel<<<(N + 255) / 256, 256, 0, stream>>>(incl, deg_i, boff, row_off,
                                                    cursor, N);
  fill_kernel<<<(E + 255) / 256, 256, 0, stream>>>(ei, cursor, csr_src, E);
  gather1_kernel<<<2048, 256, 0, stream>>>(row_off, deg_i, csr_src, xW, xWr,
                                           b1, Wl2, Wr2, pl, pr, N);
  final_kernel<<<(N + 255) / 256, 256, 0, stream>>>(row_off, deg_i, csr_src,
                                                    pl, pr, b2, out, N);
}